// Round 15
// baseline (69.750 us; speedup 1.0000x reference)
//
#include <hip/hip_runtime.h>
#include <hip/hip_bf16.h>

#define BATCH 16
#define NNODE 2048
#define NEDGE 65536
#define DIN   256
#define DOUT  256
#define KDIM  512   // 2*DIN
#define SUB   16            // sub-blocks per batch
#define ESUB  (NEDGE/SUB)   // 4096 edges per sub-block

typedef __attribute__((ext_vector_type(8))) short short8;
typedef __attribute__((ext_vector_type(4))) float f32x4;

__device__ __forceinline__ ushort f2bf(float f) {
    union { float f; unsigned u; } v; v.f = f;
    unsigned u = v.u;
    unsigned r = (u + 0x7fffu + ((u >> 16) & 1u)) >> 16;  // RNE
    return (ushort)r;
}

// int8 feature quantization, scale 16
__device__ __forceinline__ int q8(float x) {
    float c = fminf(fmaxf(x * 16.0f, -127.0f), 127.0f);
    return (int)rintf(c);
}

// fp8 e4m3fn encode (manual fallback, RNE)
__device__ __forceinline__ unsigned f2e4m3(float x) {
    unsigned u = __float_as_uint(x);
    unsigned s = (u >> 24) & 0x80u;
    float ax = __uint_as_float(u & 0x7FFFFFFFu);
    if (ax >= 448.0f) return s | 0x7Eu;
    if (ax < 0.0009765625f) return s;
    if (ax < 0.015625f) {
        int q = (int)rintf(ax * 512.0f);
        return s | (unsigned)q;
    }
    unsigned au = __float_as_uint(ax);
    int e = (int)((au >> 23) & 0xFF) - 127;
    unsigned m = au & 0x7FFFFFu;
    unsigned keep = m >> 20;
    unsigned rest = m & 0xFFFFFu;
    keep += (rest > 0x80000u) || (rest == 0x80000u && (keep & 1u));
    unsigned val = ((unsigned)(e + 7) << 3) + keep;
    if (val > 0x7Eu) val = 0x7Eu;
    return s | val;
}
template <bool HI>
__device__ __forceinline__ unsigned pk2_fp8(float a, float b, unsigned old) {
#if __has_builtin(__builtin_amdgcn_cvt_pk_fp8_f32)
    return (unsigned)__builtin_amdgcn_cvt_pk_fp8_f32(a, b, (int)old, HI);
#else
    unsigned p = f2e4m3(a) | (f2e4m3(b) << 8);
    return HI ? ((old & 0xFFFFu) | (p << 16)) : ((old & 0xFFFF0000u) | p);
#endif
}

#define ASYNC_COPY16(gsrc, ldst) \
    __builtin_amdgcn_global_load_lds((const __attribute__((address_space(1))) void*)(gsrc), \
                                     (__attribute__((address_space(3))) void*)(ldst), 16, 0, 0)

// ---------------------------------------------------------------------------
// prep (4416 blocks x 256 thr):
//   [0,256):     partial histograms (b = bid&15, sub = bid>>4)
//   [256,4352):  convert X fp32 -> bf16 (GEMM X-half) + int8 (gather)
//   [4352,4416): convert W: k<256 -> bf16 [col][512]; k>=256 -> fp8 e4m3
//                pre-arranged [kt][kq][col][8] for linear LDS staging.
// ---------------------------------------------------------------------------
__global__ __launch_bounds__(256) void prep_kernel(
        const float* __restrict__ X, const float* __restrict__ W,
        const int* __restrict__ E,
        int* __restrict__ partial,
        ushort* __restrict__ Xbf, unsigned char* __restrict__ Xi8,
        ushort* __restrict__ Wbf, unsigned char* __restrict__ Wf8s) {
    int bid = blockIdx.x;
    int t = threadIdx.x;
    if (bid < 256) {
        __shared__ int hist[NNODE];
        int b = bid & 15, sub = bid >> 4;
#pragma unroll
        for (int j = 0; j < 8; ++j) hist[t + j * 256] = 0;
        __syncthreads();
        const int4* dsts = reinterpret_cast<const int4*>(
            E + (size_t)b * 2 * NEDGE + NEDGE + sub * ESUB);
#pragma unroll
        for (int j = 0; j < 4; ++j) {
            int4 d = dsts[j * 256 + t];
            atomicAdd(&hist[d.x], 1);
            atomicAdd(&hist[d.y], 1);
            atomicAdd(&hist[d.z], 1);
            atomicAdd(&hist[d.w], 1);
        }
        __syncthreads();
        int* pb = partial + ((size_t)b * SUB + sub) * NNODE;
#pragma unroll
        for (int j = 0; j < 8; ++j) pb[t + j * 256] = hist[t + j * 256];
    } else if (bid < 4352) {
        size_t i = (size_t)(bid - 256) * 256 + t;
        const float4* p = reinterpret_cast<const float4*>(X + i * 8);
        float4 u = p[0], v = p[1];
        ushort4 o0 = { f2bf(u.x), f2bf(u.y), f2bf(u.z), f2bf(u.w) };
        ushort4 o1 = { f2bf(v.x), f2bf(v.y), f2bf(v.z), f2bf(v.w) };
        *reinterpret_cast<ushort4*>(Xbf + i * 8)     = o0;
        *reinterpret_cast<ushort4*>(Xbf + i * 8 + 4) = o1;
        unsigned q0 = (q8(u.x) & 255) | ((q8(u.y) & 255) << 8) |
                      ((q8(u.z) & 255) << 16) | ((unsigned)(q8(u.w) & 255) << 24);
        unsigned q1 = (q8(v.x) & 255) | ((q8(v.y) & 255) << 8) |
                      ((q8(v.z) & 255) << 16) | ((unsigned)(q8(v.w) & 255) << 24);
        uint2 q = { q0, q1 };
        *reinterpret_cast<uint2*>(Xi8 + i * 8) = q;
    } else {
        int i = (bid - 4352) * 256 + t;            // 0..16383
        int col = i >> 6;
        int k = (i & 63) * 8;
        const float4* p = reinterpret_cast<const float4*>(W + (size_t)col * KDIM + k);
        float4 u = p[0], v = p[1];
        if (k < DIN) {
            ushort4 o0 = { f2bf(u.x), f2bf(u.y), f2bf(u.z), f2bf(u.w) };
            ushort4 o1 = { f2bf(v.x), f2bf(v.y), f2bf(v.z), f2bf(v.w) };
            *reinterpret_cast<ushort4*>(Wbf + (size_t)col * KDIM + k)     = o0;
            *reinterpret_cast<ushort4*>(Wbf + (size_t)col * KDIM + k + 4) = o1;
        } else {
            unsigned w0 = pk2_fp8<false>(u.x, u.y, 0u);
            w0 = pk2_fp8<true>(u.z, u.w, w0);
            unsigned w1 = pk2_fp8<false>(v.x, v.y, 0u);
            w1 = pk2_fp8<true>(v.z, v.w, w1);
            int kk = k - DIN;
            int kt = kk >> 5, kq = (kk >> 3) & 3;
            uint2 qv = { w0, w1 };
            *reinterpret_cast<uint2*>(Wf8s + (size_t)kt * 8192 + kq * 2048 + col * 8) = qv;
        }
    }
}

// ---------------------------------------------------------------------------
// fillscan (256 blocks x 256 thr): per-(batch,sub) scan of partials + scatter.
// cursor ends as START offsets; counts written by sub==0.
// ---------------------------------------------------------------------------
__global__ __launch_bounds__(256) void fillscan_kernel(
        const int* __restrict__ E,
        const int* __restrict__ partial,
        int* __restrict__ counts, int* __restrict__ cursor,
        int* __restrict__ srcIdx) {
    __shared__ int cur[NNODE];
    __shared__ int tsum[256];
    int bid = blockIdx.x;
    int t = threadIdx.x;
    int b = bid & 15, sub = bid >> 4;
    const int* pb = partial + (size_t)b * SUB * NNODE;

    int tot[8] = {}, pre[8] = {};
    for (int k = 0; k < SUB; ++k) {
        const int4* p = reinterpret_cast<const int4*>(pb + k * NNODE + t * 8);
        int4 a = p[0], c = p[1];
        if (k < sub) {
            pre[0] += a.x; pre[1] += a.y; pre[2] += a.z; pre[3] += a.w;
            pre[4] += c.x; pre[5] += c.y; pre[6] += c.z; pre[7] += c.w;
        }
        tot[0] += a.x; tot[1] += a.y; tot[2] += a.z; tot[3] += a.w;
        tot[4] += c.x; tot[5] += c.y; tot[6] += c.z; tot[7] += c.w;
    }
    int s = 0;
#pragma unroll
    for (int j = 0; j < 8; ++j) s += tot[j];
    tsum[t] = s;
    __syncthreads();
    for (int off = 1; off < 256; off <<= 1) {
        int v = (t >= off) ? tsum[t - off] : 0;
        __syncthreads();
        tsum[t] += v;
        __syncthreads();
    }
    int run = (t == 0) ? 0 : tsum[t - 1];
    bool writer = (sub == 0);
    int base = b * NNODE + t * 8;
#pragma unroll
    for (int j = 0; j < 8; ++j) {
        cur[t * 8 + j] = run + pre[j];
        if (writer) { counts[base + j] = tot[j]; cursor[base + j] = run; }
        run += tot[j];
    }
    __syncthreads();

    const int* eb = E + (size_t)b * 2 * NEDGE;
    const int4* srcs = reinterpret_cast<const int4*>(eb + sub * ESUB);
    const int4* dsts = reinterpret_cast<const int4*>(eb + NEDGE + sub * ESUB);
    int* sb = srcIdx + (size_t)b * NEDGE;
#pragma unroll
    for (int j = 0; j < 4; ++j) {
        int4 sv = srcs[j * 256 + t];
        int4 dv = dsts[j * 256 + t];
        sb[atomicAdd(&cur[dv.x], 1)] = sv.x;
        sb[atomicAdd(&cur[dv.y], 1)] = sv.y;
        sb[atomicAdd(&cur[dv.z], 1)] = sv.z;
        sb[atomicAdd(&cur[dv.w], 1)] = sv.w;
    }
}

// ---------------------------------------------------------------------------
// pull-style neighbor mean over int8 features, SWAR packed-u16 accumulate
// (exact), output = fp8 e4m3 written in the swizzled 128-row panel image
// (round-13-verified layout). 8192 blocks (full TLP), quarter-wave per edge.
// ---------------------------------------------------------------------------
__global__ __launch_bounds__(256) void aggregate_kernel(
        const unsigned char* __restrict__ Xi8,
        const int* __restrict__ srcIdx,
        const int* __restrict__ cursor,
        const int* __restrict__ counts,
        unsigned char* __restrict__ Gq) {
    int bid = blockIdx.x;                     // 8192 blocks
    int blk = (bid & 7) * 1024 + (bid >> 3);  // XCD-contiguous remap (bijective)
    int wave = threadIdx.x >> 6;
    int lane = threadIdx.x & 63;
    int q = lane >> 4;                        // edge slot 0..3
    int l16 = lane & 15;                      // feature group
    int f0 = l16 * 16;                        // 16 bytes per lane
    int node = blk * 4 + wave;                // 0 .. B*N-1
    int b = node >> 11;
    int deg = counts[node];
    int start = cursor[node];
    const unsigned char* xb = Xi8 + (size_t)b * NNODE * DIN;
    const int* sidx = srcIdx + (size_t)b * NEDGE + start;

    unsigned a0 = 0, a1 = 0, a2 = 0, a3 = 0, a4 = 0, a5 = 0, a6 = 0, a7 = 0;
#define M16 0x00FF00FFu
#define ACC16(v) do {                                                         \
        unsigned w0 = (v).x ^ 0x80808080u, w1 = (v).y ^ 0x80808080u;          \
        unsigned w2 = (v).z ^ 0x80808080u, w3 = (v).w ^ 0x80808080u;          \
        a0 += w0 & M16;  a1 += (w0 >> 8) & M16;                               \
        a2 += w1 & M16;  a3 += (w1 >> 8) & M16;                               \
        a4 += w2 & M16;  a5 += (w2 >> 8) & M16;                               \
        a6 += w3 & M16;  a7 += (w3 >> 8) & M16;                               \
    } while (0)

    int i = 0;
    for (; i + 16 <= deg; i += 16) {
        int s0 = sidx[i + q], s1 = sidx[i + 4 + q];
        int s2 = sidx[i + 8 + q], s3 = sidx[i + 12 + q];
        uint4 v0 = *reinterpret_cast<const uint4*>(xb + (size_t)s0 * DIN + f0);
        uint4 v1 = *reinterpret_cast<const uint4*>(xb + (size_t)s1 * DIN + f0);
        uint4 v2 = *reinterpret_cast<const uint4*>(xb + (size_t)s2 * DIN + f0);
        uint4 v3 = *reinterpret_cast<const uint4*>(xb + (size_t)s3 * DIN + f0);
        ACC16(v0); ACC16(v1); ACC16(v2); ACC16(v3);
    }
    for (; i < deg; i += 4) {
        int e = i + q;
        uint4 v = { 0x80808080u, 0x80808080u, 0x80808080u, 0x80808080u };
        if (e < deg)
            v = *reinterpret_cast<const uint4*>(xb + (size_t)sidx[e] * DIN + f0);
        ACC16(v);
    }
#undef ACC16
#undef M16
    a0 += (unsigned)__shfl_xor((int)a0, 16, 64); a0 += (unsigned)__shfl_xor((int)a0, 32, 64);
    a1 += (unsigned)__shfl_xor((int)a1, 16, 64); a1 += (unsigned)__shfl_xor((int)a1, 32, 64);
    a2 += (unsigned)__shfl_xor((int)a2, 16, 64); a2 += (unsigned)__shfl_xor((int)a2, 32, 64);
    a3 += (unsigned)__shfl_xor((int)a3, 16, 64); a3 += (unsigned)__shfl_xor((int)a3, 32, 64);
    a4 += (unsigned)__shfl_xor((int)a4, 16, 64); a4 += (unsigned)__shfl_xor((int)a4, 32, 64);
    a5 += (unsigned)__shfl_xor((int)a5, 16, 64); a5 += (unsigned)__shfl_xor((int)a5, 32, 64);
    a6 += (unsigned)__shfl_xor((int)a6, 16, 64); a6 += (unsigned)__shfl_xor((int)a6, 32, 64);
    a7 += (unsigned)__shfl_xor((int)a7, 16, 64); a7 += (unsigned)__shfl_xor((int)a7, 32, 64);

    if (q == 0) {
        float sc = 1.0f / (16.0f * (float)max(deg, 1));
        float bs = 128.0f * (float)deg;
        float f[16];
        f[ 0] = ((float)(int)(a0 & 0xFFFFu) - bs) * sc;
        f[ 2] = ((float)(int)(a0 >> 16)     - bs) * sc;
        f[ 1] = ((float)(int)(a1 & 0xFFFFu) - bs) * sc;
        f[ 3] = ((float)(int)(a1 >> 16)     - bs) * sc;
        f[ 4] = ((float)(int)(a2 & 0xFFFFu) - bs) * sc;
        f[ 6] = ((float)(int)(a2 >> 16)     - bs) * sc;
        f[ 5] = ((float)(int)(a3 & 0xFFFFu) - bs) * sc;
        f[ 7] = ((float)(int)(a3 >> 16)     - bs) * sc;
        f[ 8] = ((float)(int)(a4 & 0xFFFFu) - bs) * sc;
        f[10] = ((float)(int)(a4 >> 16)     - bs) * sc;
        f[ 9] = ((float)(int)(a5 & 0xFFFFu) - bs) * sc;
        f[11] = ((float)(int)(a5 >> 16)     - bs) * sc;
        f[12] = ((float)(int)(a6 & 0xFFFFu) - bs) * sc;
        f[14] = ((float)(int)(a6 >> 16)     - bs) * sc;
        f[13] = ((float)(int)(a7 & 0xFFFFu) - bs) * sc;
        f[15] = ((float)(int)(a7 >> 16)     - bs) * sc;
        unsigned wds[4];
#pragma unroll
        for (int w = 0; w < 4; ++w) {
            unsigned t0 = pk2_fp8<false>(f[4 * w], f[4 * w + 1], 0u);
            wds[w] = pk2_fp8<true>(f[4 * w + 2], f[4 * w + 3], t0);
        }
        int panel = node >> 7, r = node & 127;
        int slot = l16 ^ ((r >> 1) & 7);
        uint4 val;
        if (r & 1) { val.x = wds[2]; val.y = wds[3]; val.z = wds[0]; val.w = wds[1]; }
        else       { val.x = wds[0]; val.y = wds[1]; val.z = wds[2]; val.w = wds[3]; }
        *reinterpret_cast<uint4*>(
            Gq + ((size_t)panel * 2048 + r * 16 + slot) * 16) = val;
    }
}

// ---------------------------------------------------------------------------
// bf16+fp8 MFMA GEMM: 64x256 tile (full DOUT -> A panel read ONCE), 512
// blocks (2/CU preserved), 256 thr / 4 waves, each wave 64x64 output.
// t<8: bf16 K-steps; Gq slice (16KB) staged over t=0..3 (1 wave-copy each).
// t>=8: fp8 K-steps: A from LDS Gq, B = 8KB fp8 W tiles double-buffered in
// the dead low half of Bs. Counted per-wave vmcnt: 6,6,6,6,5,5,5,2,...,0.
// LDS = 8 + 32 + 16 = 56 KB -> 2 blocks/CU.
// ---------------------------------------------------------------------------
__global__ __launch_bounds__(256) void gemm_kernel(
        const ushort* __restrict__ Xbf,
        const unsigned char* __restrict__ Gq,
        const ushort* __restrict__ Wbf,
        const unsigned char* __restrict__ Wf8s,
        const float* __restrict__ bias,
        float* __restrict__ out) {
    __shared__ ushort As[2][64 * 32];    // 8 KB
    __shared__ ushort Bs[2][256 * 32];   // 32 KB; low 8KB of each aliased by fp8 W
    __shared__ uint4  GqV[1024];         // 16 KB (64-row fp8 slice)

    const int tid = threadIdx.x;
    const int wid = tid >> 6, lane = tid & 63;   // wid = col-strip 0..3

    int orig = blockIdx.x;
    int logical = (orig & 7) * 64 + (orig >> 3);  // XCD-chunked bijective, 512
    const int rowBase = logical * 64;

    f32x4 acc[4][4] = {};

    // staging geometry: As = 64 rows x 32k, 1 copy/thread
    const int sr = tid >> 2;                       // row 0..63
    const int lk = (((tid & 3) ^ ((tid >> 3) & 3)) * 8);  // pre-swizzled chunk
    const ushort* Arow = Xbf + (size_t)rowBase * DIN;
    const unsigned char* GqSlice = Gq + (size_t)(logical >> 1) * 32768
                                      + (size_t)(logical & 1) * 16384;

#define STAGE_X(k0, buf) do {                                                  \
        ASYNC_COPY16(Arow + (size_t)sr * DIN + (k0) + lk,                      \
                     &As[buf][wid * 512]);                                     \
        _Pragma("unroll")                                                      \
        for (int p = 0; p < 4; ++p)                                            \
            ASYNC_COPY16(Wbf + (size_t)(p * 64 + sr) * KDIM + (k0) + lk,       \
                         &Bs[buf][p * 2048 + wid * 512]);                      \
    } while (0)
#define GQ_STAGE(t4) \
        ASYNC_COPY16(GqSlice + (t4) * 4096 + wid * 1024 + lane * 16, \
                     (char*)GqV + (t4) * 4096 + wid * 1024)
#define SG8_STAGE(kt) do {                                                     \
        _Pragma("unroll")                                                      \
        for (int j = 0; j < 2; ++j)                                            \
            ASYNC_COPY16(Wf8s + (size_t)(kt) * 8192 + wid * 2048 + j * 1024    \
                             + lane * 16,                                      \
                         (char*)&Bs[(kt) & 1][0] + wid * 2048 + j * 1024);     \
    } while (0)

    const int fl = lane & 15;
    const int kq = lane >> 4;
    const int fc = (kq ^ ((fl >> 1) & 3)) * 8;     // bf16 fragment chunk
    const long* GqL = reinterpret_cast<const long*>(GqV);

    STAGE_X(0, 0);
    for (int t = 0; t < 16; ++t) {
        if (t < 4) {
            GQ_STAGE(t);
            STAGE_X((t + 1) * 32, (t + 1) & 1);
            asm volatile("s_waitcnt vmcnt(6)" ::: "memory");
        } else if (t < 7) {
            STAGE_X((t + 1) * 32, (t + 1) & 1);
            asm volatile("s_waitcnt vmcnt(5)" ::: "memory");
        } else if (t == 7) {
            SG8_STAGE(0);
            asm volatile("s_waitcnt vmcnt(2)" ::: "memory");
        } else if (t < 15) {
            SG8_STAGE(t - 7);
            asm volatile("s_waitcnt vmcnt(2)" ::: "memory");
        } else {
            asm volatile("s_waitcnt vmcnt(0)" ::: "memory");
        }
        __builtin_amdgcn_s_barrier();

        if (t < 8) {
            const int bufx = t & 1;
            short8 a[4], bb[4];
#pragma unroll
            for (int m = 0; m < 4; ++m)
                a[m] = *reinterpret_cast<const short8*>(
                    &As[bufx][(m * 16 + fl) * 32 + fc]);
#pragma unroll
            for (int n = 0; n < 4; ++n)
                bb[n] = *reinterpret_cast<const short8*>(
                    &Bs[bufx][(wid * 64 + n * 16 + fl) * 32 + fc]);
#pragma unroll
            for (int m = 0; m < 4; ++m)
#pragma unroll
                for (int n = 0; n < 4; ++n)
                    acc[m][n] = __builtin_amdgcn_mfma_f32_16x16x32_bf16(
                        a[m], bb[n], acc[m][n], 0, 0, 0);
        } else {
            const int kt = t - 8;
            const unsigned char* Bf8 =
                reinterpret_cast<const unsigned char*>(&Bs[kt & 1][0]);
            long ag[4], bg[4];
#pragma unroll
            for (int m = 0; m < 4; ++m) {
                int r = m * 16 + fl;                  // 0..63
                ag[m] = GqL[r * 32 + ((kt * 4 + kq) ^ (r & 15))];
            }
#pragma unroll
            for (int n = 0; n < 4; ++n) {
                int c = wid * 64 + n * 16 + fl;       // 0..255
                bg[n] = *reinterpret_cast<const long*>(Bf8 + kq * 2048 + c * 8);
            }
#pragma unroll
            for (int m = 0; m < 4; ++m)
#pragma unroll
                for (int n = 0; n < 4; ++n)
                    acc[m][n] = __builtin_amdgcn_mfma_f32_16x16x32_fp8_fp8(
                        ag[m], bg[n], acc[m][n], 0, 0, 0);
        }
        __builtin_amdgcn_s_barrier();
    }
#undef STAGE_X
#undef GQ_STAGE
#undef SG8_STAGE

    // epilogue: C/D layout col=lane&15, row=(lane>>4)*4+reg
    const int cl = lane & 15, rq = lane >> 4;
#pragma unroll
    for (int n = 0; n < 4; ++n) {
        int col = wid * 64 + n * 16 + cl;
        float bv = bias[col];
#pragma unroll
        for (int m = 0; m < 4; ++m) {
            int r0o = rowBase + m * 16 + rq * 4;
#pragma unroll
            for (int j = 0; j < 4; ++j)
                out[(size_t)(r0o + j) * DOUT + col] = acc[m][n][j] + bv;
        }
    }
}

// ---------------------------------------------------------------------------
extern "C" void kernel_launch(void* const* d_in, const int* in_sizes, int n_in,
                              void* d_out, int out_size, void* d_ws, size_t ws_size,
                              hipStream_t stream) {
    const float* X    = (const float*)d_in[0];   // (B, N, DIN)
    const int*   E    = (const int*)d_in[1];     // (B, 2, NEDGE) int32
    const float* W    = (const float*)d_in[2];   // (DOUT, KDIM)
    const float* bias = (const float*)d_in[3];   // (DOUT,)
    float* out = (float*)d_out;                  // (B, N, DOUT)

    char* ws = (char*)d_ws;
    ushort* Xbf  = (ushort*)ws;                                       // 16.78 MB
    unsigned char* Xi8 = (unsigned char*)(Xbf + (size_t)BATCH * NNODE * DIN); // 8.39 MB
    ushort* Wbf  = (ushort*)(Xi8 + (size_t)BATCH * NNODE * DIN);      // 512 KB
    unsigned char* Wf8s = (unsigned char*)(Wbf + (size_t)DOUT * KDIM);// 64 KB
    int* counts  = (int*)(Wf8s + 8 * 8192);                           // 128 KB
    int* cursor  = counts + BATCH * NNODE;                            // 128 KB
    int* srcIdx  = cursor + BATCH * NNODE;                            // 4 MB
    int* partial = srcIdx + (size_t)BATCH * NEDGE;                    // 2 MB
    unsigned char* Gq = (unsigned char*)(partial + (size_t)BATCH * SUB * NNODE); // 8.39 MB

    // partial hists (256) + convert X bf16+i8 (4096) + convert W bf16/fp8 (64)
    prep_kernel<<<4416, 256, 0, stream>>>(X, W, E, partial, Xbf, Xi8, Wbf, Wf8s);

    fillscan_kernel<<<256, 256, 0, stream>>>(E, partial, counts, cursor, srcIdx);

    aggregate_kernel<<<(BATCH * NNODE) / 4, 256, 0, stream>>>(
        Xi8, srcIdx, cursor, counts, Gq);

    dim3 ggrid(512);
    gemm_kernel<<<ggrid, 256, 0, stream>>>(Xbf, Gq, Wbf, Wf8s, bias, out);
}

// Round 16
// 66.405 us; speedup vs baseline: 1.0504x; 1.0504x over previous
//
#include <hip/hip_runtime.h>
#include <hip/hip_bf16.h>

#define BATCH 16
#define NNODE 2048
#define NEDGE 65536
#define DIN   256
#define DOUT  256
#define KDIM  512   // 2*DIN
#define SUB   16            // sub-blocks per batch
#define ESUB  (NEDGE/SUB)   // 4096 edges per sub-block

typedef __attribute__((ext_vector_type(8))) short short8;
typedef __attribute__((ext_vector_type(8))) ushort ushort8;
typedef __attribute__((ext_vector_type(4))) float f32x4;

__device__ __forceinline__ ushort f2bf(float f) {
    union { float f; unsigned u; } v; v.f = f;
    unsigned u = v.u;
    unsigned r = (u + 0x7fffu + ((u >> 16) & 1u)) >> 16;  // RNE
    return (ushort)r;
}

// int8 feature quantization, scale 16 (step 1/16; |x|<=7.9 unclamped)
__device__ __forceinline__ int q8(float x) {
    float c = fminf(fmaxf(x * 16.0f, -127.0f), 127.0f);
    return (int)rintf(c);
}

#define ASYNC_COPY16(gsrc, ldst) \
    __builtin_amdgcn_global_load_lds((const __attribute__((address_space(1))) void*)(gsrc), \
                                     (__attribute__((address_space(3))) void*)(ldst), 16, 0, 0)

// ---------------------------------------------------------------------------
// hist (256 blocks x 256 thr): partial histograms (b = bid&15, sub = bid>>4):
// private LDS hist of 4K edges -> plain-write partial[b][sub][*]. Runs alone
// (short); the BW-bound converts moved to the next dispatch to overlap
// fillscan instead.
// ---------------------------------------------------------------------------
__global__ __launch_bounds__(256) void hist_kernel(
        const int* __restrict__ E, int* __restrict__ partial) {
    __shared__ int hist[NNODE];
    int bid = blockIdx.x;
    int t = threadIdx.x;
    int b = bid & 15, sub = bid >> 4;
#pragma unroll
    for (int j = 0; j < 8; ++j) hist[t + j * 256] = 0;
    __syncthreads();
    const int4* dsts = reinterpret_cast<const int4*>(
        E + (size_t)b * 2 * NEDGE + NEDGE + sub * ESUB);
#pragma unroll
    for (int j = 0; j < 4; ++j) {
        int4 d = dsts[j * 256 + t];
        atomicAdd(&hist[d.x], 1);
        atomicAdd(&hist[d.y], 1);
        atomicAdd(&hist[d.z], 1);
        atomicAdd(&hist[d.w], 1);
    }
    __syncthreads();
    int* pb = partial + ((size_t)b * SUB + sub) * NNODE;
#pragma unroll
    for (int j = 0; j < 8; ++j) pb[t + j * 256] = hist[t + j * 256];
}

// ---------------------------------------------------------------------------
// fillconv (4416 blocks x 256 thr):
//   [0,256):     fillscan — block (b = bid&15, sub = bid>>4) re-derives its
//                batch's node scan from the 16 partials, seeds an LDS cursor
//                with its own sub-window, scatters its 4K edges. sub==0
//                blocks write counts + cursor (start offsets).
//   [256,4352):  convert X fp32 -> bf16 + int8 — overlaps the fillscan.
//   [4352,4416): convert W fp32 -> bf16.
// ---------------------------------------------------------------------------
__global__ __launch_bounds__(256) void fillconv_kernel(
        const float* __restrict__ X, const float* __restrict__ W,
        const int* __restrict__ E,
        const int* __restrict__ partial,
        int* __restrict__ counts, int* __restrict__ cursor,
        int* __restrict__ srcIdx,
        ushort* __restrict__ Xbf, unsigned char* __restrict__ Xi8,
        ushort* __restrict__ Wbf) {
    int bid = blockIdx.x;
    int t = threadIdx.x;
    if (bid < 256) {
        __shared__ int cur[NNODE];
        __shared__ int tsum[256];
        int b = bid & 15, sub = bid >> 4;
        const int* pb = partial + (size_t)b * SUB * NNODE;

        int tot[8] = {}, pre[8] = {};
        for (int k = 0; k < SUB; ++k) {
            const int4* p = reinterpret_cast<const int4*>(pb + k * NNODE + t * 8);
            int4 a = p[0], c = p[1];
            if (k < sub) {
                pre[0] += a.x; pre[1] += a.y; pre[2] += a.z; pre[3] += a.w;
                pre[4] += c.x; pre[5] += c.y; pre[6] += c.z; pre[7] += c.w;
            }
            tot[0] += a.x; tot[1] += a.y; tot[2] += a.z; tot[3] += a.w;
            tot[4] += c.x; tot[5] += c.y; tot[6] += c.z; tot[7] += c.w;
        }
        int s = 0;
#pragma unroll
        for (int j = 0; j < 8; ++j) s += tot[j];
        tsum[t] = s;
        __syncthreads();
        for (int off = 1; off < 256; off <<= 1) {
            int v = (t >= off) ? tsum[t - off] : 0;
            __syncthreads();
            tsum[t] += v;
            __syncthreads();
        }
        int run = (t == 0) ? 0 : tsum[t - 1];
        bool writer = (sub == 0);
        int base = b * NNODE + t * 8;
#pragma unroll
        for (int j = 0; j < 8; ++j) {
            cur[t * 8 + j] = run + pre[j];
            if (writer) { counts[base + j] = tot[j]; cursor[base + j] = run; }
            run += tot[j];
        }
        __syncthreads();

        const int* eb = E + (size_t)b * 2 * NEDGE;
        const int4* srcs = reinterpret_cast<const int4*>(eb + sub * ESUB);
        const int4* dsts = reinterpret_cast<const int4*>(eb + NEDGE + sub * ESUB);
        int* sb = srcIdx + (size_t)b * NEDGE;
#pragma unroll
        for (int j = 0; j < 4; ++j) {
            int4 sv = srcs[j * 256 + t];
            int4 dv = dsts[j * 256 + t];
            sb[atomicAdd(&cur[dv.x], 1)] = sv.x;
            sb[atomicAdd(&cur[dv.y], 1)] = sv.y;
            sb[atomicAdd(&cur[dv.z], 1)] = sv.z;
            sb[atomicAdd(&cur[dv.w], 1)] = sv.w;
        }
    } else if (bid < 4352) {
        size_t i = (size_t)(bid - 256) * 256 + t;
        const float4* p = reinterpret_cast<const float4*>(X + i * 8);
        float4 u = p[0], v = p[1];
        ushort4 o0 = { f2bf(u.x), f2bf(u.y), f2bf(u.z), f2bf(u.w) };
        ushort4 o1 = { f2bf(v.x), f2bf(v.y), f2bf(v.z), f2bf(v.w) };
        *reinterpret_cast<ushort4*>(Xbf + i * 8)     = o0;
        *reinterpret_cast<ushort4*>(Xbf + i * 8 + 4) = o1;
        unsigned q0 = (q8(u.x) & 255) | ((q8(u.y) & 255) << 8) |
                      ((q8(u.z) & 255) << 16) | ((unsigned)(q8(u.w) & 255) << 24);
        unsigned q1 = (q8(v.x) & 255) | ((q8(v.y) & 255) << 8) |
                      ((q8(v.z) & 255) << 16) | ((unsigned)(q8(v.w) & 255) << 24);
        uint2 q = { q0, q1 };
        *reinterpret_cast<uint2*>(Xi8 + i * 8) = q;
    } else {
        size_t i = (size_t)(bid - 4352) * 256 + t;
        const float4* p = reinterpret_cast<const float4*>(W + i * 8);
        float4 u = p[0], v = p[1];
        ushort4 o0 = { f2bf(u.x), f2bf(u.y), f2bf(u.z), f2bf(u.w) };
        ushort4 o1 = { f2bf(v.x), f2bf(v.y), f2bf(v.z), f2bf(v.w) };
        *reinterpret_cast<ushort4*>(Wbf + i * 8)     = o0;
        *reinterpret_cast<ushort4*>(Wbf + i * 8 + 4) = o1;
    }
}

// ---------------------------------------------------------------------------
// pull-style neighbor mean over int8 features (scale 16), SWAR packed-u16
// integer accumulate (exact), bf16 output. One wave per node; QUARTER-wave
// per edge: lane = 16*q + l16; l16 owns 16 features (uint4 = one full row
// per wave-instruction). Tail pads with 0x80808080 (debias-exact 0).
// Fields <= 255*70 << 65536. XCD swizzle: 2 batches per XCD.
// ---------------------------------------------------------------------------
__global__ __launch_bounds__(256) void aggregate_kernel(
        const unsigned char* __restrict__ Xi8,
        const int* __restrict__ srcIdx,
        const int* __restrict__ cursor,
        const int* __restrict__ counts,
        ushort* __restrict__ Gbf) {
    int bid = blockIdx.x;                     // 8192 blocks
    int blk = (bid & 7) * 1024 + (bid >> 3);  // XCD-contiguous remap (bijective)
    int wave = threadIdx.x >> 6;
    int lane = threadIdx.x & 63;
    int q = lane >> 4;                        // edge slot 0..3
    int l16 = lane & 15;                      // feature group
    int f0 = l16 * 16;                        // 16 bytes (features) per lane
    int node = blk * 4 + wave;                // 0 .. B*N-1
    int b = node >> 11;
    int deg = counts[node];
    int start = cursor[node];
    const unsigned char* xb = Xi8 + (size_t)b * NNODE * DIN;
    const int* sidx = srcIdx + (size_t)b * NEDGE + start;

    unsigned a0 = 0, a1 = 0, a2 = 0, a3 = 0, a4 = 0, a5 = 0, a6 = 0, a7 = 0;
#define M16 0x00FF00FFu
#define ACC16(v) do {                                                         \
        unsigned w0 = (v).x ^ 0x80808080u, w1 = (v).y ^ 0x80808080u;          \
        unsigned w2 = (v).z ^ 0x80808080u, w3 = (v).w ^ 0x80808080u;          \
        a0 += w0 & M16;  a1 += (w0 >> 8) & M16;                               \
        a2 += w1 & M16;  a3 += (w1 >> 8) & M16;                               \
        a4 += w2 & M16;  a5 += (w2 >> 8) & M16;                               \
        a6 += w3 & M16;  a7 += (w3 >> 8) & M16;                               \
    } while (0)

    int i = 0;
    for (; i + 16 <= deg; i += 16) {
        int s0 = sidx[i + q], s1 = sidx[i + 4 + q];
        int s2 = sidx[i + 8 + q], s3 = sidx[i + 12 + q];
        uint4 v0 = *reinterpret_cast<const uint4*>(xb + (size_t)s0 * DIN + f0);
        uint4 v1 = *reinterpret_cast<const uint4*>(xb + (size_t)s1 * DIN + f0);
        uint4 v2 = *reinterpret_cast<const uint4*>(xb + (size_t)s2 * DIN + f0);
        uint4 v3 = *reinterpret_cast<const uint4*>(xb + (size_t)s3 * DIN + f0);
        ACC16(v0); ACC16(v1); ACC16(v2); ACC16(v3);
    }
    for (; i < deg; i += 4) {
        int e = i + q;
        uint4 v = { 0x80808080u, 0x80808080u, 0x80808080u, 0x80808080u };
        if (e < deg) {
            int s0 = sidx[e];
            v = *reinterpret_cast<const uint4*>(xb + (size_t)s0 * DIN + f0);
        }
        ACC16(v);
    }
#undef ACC16
#undef M16
    a0 += (unsigned)__shfl_xor((int)a0, 16, 64); a0 += (unsigned)__shfl_xor((int)a0, 32, 64);
    a1 += (unsigned)__shfl_xor((int)a1, 16, 64); a1 += (unsigned)__shfl_xor((int)a1, 32, 64);
    a2 += (unsigned)__shfl_xor((int)a2, 16, 64); a2 += (unsigned)__shfl_xor((int)a2, 32, 64);
    a3 += (unsigned)__shfl_xor((int)a3, 16, 64); a3 += (unsigned)__shfl_xor((int)a3, 32, 64);
    a4 += (unsigned)__shfl_xor((int)a4, 16, 64); a4 += (unsigned)__shfl_xor((int)a4, 32, 64);
    a5 += (unsigned)__shfl_xor((int)a5, 16, 64); a5 += (unsigned)__shfl_xor((int)a5, 32, 64);
    a6 += (unsigned)__shfl_xor((int)a6, 16, 64); a6 += (unsigned)__shfl_xor((int)a6, 32, 64);
    a7 += (unsigned)__shfl_xor((int)a7, 16, 64); a7 += (unsigned)__shfl_xor((int)a7, 32, 64);

    if (q == 0) {
        float sc = 1.0f / (16.0f * (float)max(deg, 1));   // undo scale-16
        float bias = 128.0f * (float)deg;
        // byte j of word w = feature w*4+j; a(2w)=bytes{0,2}, a(2w+1)=bytes{1,3}
        float f[16];
        f[ 0] = ((float)(int)(a0 & 0xFFFFu) - bias) * sc;
        f[ 2] = ((float)(int)(a0 >> 16)     - bias) * sc;
        f[ 1] = ((float)(int)(a1 & 0xFFFFu) - bias) * sc;
        f[ 3] = ((float)(int)(a1 >> 16)     - bias) * sc;
        f[ 4] = ((float)(int)(a2 & 0xFFFFu) - bias) * sc;
        f[ 6] = ((float)(int)(a2 >> 16)     - bias) * sc;
        f[ 5] = ((float)(int)(a3 & 0xFFFFu) - bias) * sc;
        f[ 7] = ((float)(int)(a3 >> 16)     - bias) * sc;
        f[ 8] = ((float)(int)(a4 & 0xFFFFu) - bias) * sc;
        f[10] = ((float)(int)(a4 >> 16)     - bias) * sc;
        f[ 9] = ((float)(int)(a5 & 0xFFFFu) - bias) * sc;
        f[11] = ((float)(int)(a5 >> 16)     - bias) * sc;
        f[12] = ((float)(int)(a6 & 0xFFFFu) - bias) * sc;
        f[14] = ((float)(int)(a6 >> 16)     - bias) * sc;
        f[13] = ((float)(int)(a7 & 0xFFFFu) - bias) * sc;
        f[15] = ((float)(int)(a7 >> 16)     - bias) * sc;
        ushort8 o0, o1;
#pragma unroll
        for (int j = 0; j < 8; ++j) { o0[j] = f2bf(f[j]); o1[j] = f2bf(f[j + 8]); }
        ushort* gp = Gbf + (size_t)node * DIN + f0;
        *reinterpret_cast<ushort8*>(gp)     = o0;
        *reinterpret_cast<ushort8*>(gp + 8) = o1;
    }
}

// ---------------------------------------------------------------------------
// bf16 MFMA GEMM (round-11 best config): 128x128 tile, BK=32, 512 blocks,
// TRIPLE-buffered LDS with 2-deep prefetch (STAGE t+2, vmcnt(8)).
// Chunk-XOR LDS swizzle both sides. LDS 48 KB -> 2 blocks/CU.
// ---------------------------------------------------------------------------
__global__ __launch_bounds__(256) void gemm_kernel(
        const ushort* __restrict__ Xbf,
        const ushort* __restrict__ Gbf,
        const ushort* __restrict__ Wbf,
        const float* __restrict__ bias,
        float* __restrict__ out) {
    __shared__ ushort As[3][128 * 32];   // [buf][row*32 + k]
    __shared__ ushort Bs[3][128 * 32];
    const int tid = threadIdx.x;
    const int wid = tid >> 6, lane = tid & 63;

    int orig = blockIdx.x;
    int logical = (orig & 7) * 64 + (orig >> 3);
    int bx = logical >> 1;
    int by = logical & 1;
    const int rowBase = bx * 128;
    const int colBase = by * 128;
    const int wm = wid >> 1, wn = wid & 1;

    f32x4 acc[4][4] = {};

    const int lr = lane >> 2;                      // staging row-within-16
    const int lk = (((lane & 3) ^ ((lane >> 3) & 3)) * 8);  // pre-swizzled chunk

    const ushort* Arow = Xbf + (size_t)rowBase * DIN;
    const ushort* Grow = Gbf + (size_t)rowBase * DIN;
    const ushort* Brow = Wbf + (size_t)colBase * KDIM;
    const int r0 = wid * 16 + lr;

#define STAGE(k0, buf) do {                                                   \
        const ushort* Ab = ((k0) < DIN) ? (Arow + (k0)) : (Grow + ((k0) - DIN)); \
        const ushort* Bb = Brow + (k0);                                       \
        ASYNC_COPY16(Ab + (size_t)r0 * DIN + lk,          &As[buf][wid * 512]);       \
        ASYNC_COPY16(Ab + (size_t)(r0 + 64) * DIN + lk,   &As[buf][2048 + wid * 512]);\
        ASYNC_COPY16(Bb + (size_t)r0 * KDIM + lk,         &Bs[buf][wid * 512]);       \
        ASYNC_COPY16(Bb + (size_t)(r0 + 64) * KDIM + lk,  &Bs[buf][2048 + wid * 512]);\
    } while (0)

    const int fl = lane & 15;
    const int fc = ((lane >> 4) ^ ((fl >> 1) & 3)) * 8;    // swizzled fragment chunk

    STAGE(0, 0);
    STAGE(32, 1);
    for (int t = 0; t < 16; ++t) {
        const int bt = t % 3;
        if (t + 2 < 16) {
            STAGE((t + 2) * 32, (t + 2) % 3);
            asm volatile("s_waitcnt vmcnt(8)" ::: "memory");   // tile t landed
        } else if (t + 1 < 16) {
            asm volatile("s_waitcnt vmcnt(4)" ::: "memory");
        } else {
            asm volatile("s_waitcnt vmcnt(0)" ::: "memory");
        }
        __builtin_amdgcn_s_barrier();

        short8 a[4], b[4];
#pragma unroll
        for (int m = 0; m < 4; ++m)
            a[m] = *reinterpret_cast<const short8*>(
                &As[bt][(wm * 64 + m * 16 + fl) * 32 + fc]);
#pragma unroll
        for (int n = 0; n < 4; ++n)
            b[n] = *reinterpret_cast<const short8*>(
                &Bs[bt][(wn * 64 + n * 16 + fl) * 32 + fc]);
#pragma unroll
        for (int m = 0; m < 4; ++m)
#pragma unroll
            for (int n = 0; n < 4; ++n)
                acc[m][n] = __builtin_amdgcn_mfma_f32_16x16x32_bf16(
                    a[m], b[n], acc[m][n], 0, 0, 0);
        __builtin_amdgcn_s_barrier();
    }
#undef STAGE

    const int cl = lane & 15, rq = lane >> 4;
#pragma unroll
    for (int n = 0; n < 4; ++n) {
        int col = colBase + wn * 64 + n * 16 + cl;
        float bv = bias[col];
#pragma unroll
        for (int m = 0; m < 4; ++m) {
            int r0o = rowBase + wm * 64 + m * 16 + rq * 4;
#pragma unroll
            for (int j = 0; j < 4; ++j)
                out[(size_t)(r0o + j) * DOUT + col] = acc[m][n][j] + bv;
        }
    }
}

// ---------------------------------------------------------------------------
extern "C" void kernel_launch(void* const* d_in, const int* in_sizes, int n_in,
                              void* d_out, int out_size, void* d_ws, size_t ws_size,
                              hipStream_t stream) {
    const float* X    = (const float*)d_in[0];   // (B, N, DIN)
    const int*   E    = (const int*)d_in[1];     // (B, 2, NEDGE) int32
    const float* W    = (const float*)d_in[2];   // (DOUT, KDIM)
    const float* bias = (const float*)d_in[3];   // (DOUT,)
    float* out = (float*)d_out;                  // (B, N, DOUT)

    char* ws = (char*)d_ws;
    ushort* Xbf  = (ushort*)ws;                                 // 16.78 MB
    ushort* Gbf  = Xbf + (size_t)BATCH * NNODE * DIN;           // 16.78 MB
    ushort* Wbf  = Gbf + (size_t)BATCH * NNODE * DIN;           // 256 KB
    int* counts  = (int*)(Wbf + (size_t)DOUT * KDIM);           // 128 KB
    int* cursor  = counts + BATCH * NNODE;                      // 128 KB
    int* srcIdx  = cursor + BATCH * NNODE;                      // 4 MB
    unsigned char* Xi8 = (unsigned char*)(srcIdx + (size_t)BATCH * NEDGE); // 8.39 MB
    // partial overlays into Gbf (dead until aggregate writes it)
    int* partial = (int*)Gbf;                                   // 2 MB

    // 1: partial histograms only (short)
    hist_kernel<<<256, 256, 0, stream>>>(E, partial);

    // 2: fillscan (256 blocks) overlapped with X/W converts (4160 blocks)
    fillconv_kernel<<<4416, 256, 0, stream>>>(
        X, W, E, partial, counts, cursor, srcIdx, Xbf, Xi8, Wbf);

    // 3: int8 SWAR gather-mean -> bf16 G
    aggregate_kernel<<<(BATCH * NNODE) / 4, 256, 0, stream>>>(
        Xi8, srcIdx, cursor, counts, Gbf);

    // 4: bf16 MFMA GEMM
    dim3 ggrid(512);
    gemm_kernel<<<ggrid, 256, 0, stream>>>(Xbf, Gbf, Wbf, bias, out);
}

// Round 17
// 63.832 us; speedup vs baseline: 1.0927x; 1.0403x over previous
//
#include <hip/hip_runtime.h>
#include <hip/hip_bf16.h>

#define BATCH 16
#define NNODE 2048
#define NEDGE 65536
#define DIN   256
#define DOUT  256
#define KDIM  512   // 2*DIN
#define SUB   16            // sub-blocks per batch
#define ESUB  (NEDGE/SUB)   // 4096 edges per sub-block

typedef __attribute__((ext_vector_type(8))) short short8;
typedef __attribute__((ext_vector_type(8))) ushort ushort8;
typedef __attribute__((ext_vector_type(4))) float f32x4;

__device__ __forceinline__ ushort f2bf(float f) {
    union { float f; unsigned u; } v; v.f = f;
    unsigned u = v.u;
    unsigned r = (u + 0x7fffu + ((u >> 16) & 1u)) >> 16;  // RNE
    return (ushort)r;
}

// int8 feature quantization, scale 16 (step 1/16; |x|<=7.9 unclamped)
__device__ __forceinline__ int q8(float x) {
    float c = fminf(fmaxf(x * 16.0f, -127.0f), 127.0f);
    return (int)rintf(c);
}

#define ASYNC_COPY16(gsrc, ldst) \
    __builtin_amdgcn_global_load_lds((const __attribute__((address_space(1))) void*)(gsrc), \
                                     (__attribute__((address_space(3))) void*)(ldst), 16, 0, 0)

// ---------------------------------------------------------------------------
// hist (256 blocks x 256 thr): partial histograms (b = bid&15, sub = bid>>4):
// private LDS hist of 4K edges -> plain-write partial[b][sub][*].
// ---------------------------------------------------------------------------
__global__ __launch_bounds__(256) void hist_kernel(
        const int* __restrict__ E, int* __restrict__ partial) {
    __shared__ int hist[NNODE];
    int bid = blockIdx.x;
    int t = threadIdx.x;
    int b = bid & 15, sub = bid >> 4;
#pragma unroll
    for (int j = 0; j < 8; ++j) hist[t + j * 256] = 0;
    __syncthreads();
    const int4* dsts = reinterpret_cast<const int4*>(
        E + (size_t)b * 2 * NEDGE + NEDGE + sub * ESUB);
#pragma unroll
    for (int j = 0; j < 4; ++j) {
        int4 d = dsts[j * 256 + t];
        atomicAdd(&hist[d.x], 1);
        atomicAdd(&hist[d.y], 1);
        atomicAdd(&hist[d.z], 1);
        atomicAdd(&hist[d.w], 1);
    }
    __syncthreads();
    int* pb = partial + ((size_t)b * SUB + sub) * NNODE;
#pragma unroll
    for (int j = 0; j < 8; ++j) pb[t + j * 256] = hist[t + j * 256];
}

// ---------------------------------------------------------------------------
// fillconv (4416 blocks x 256 thr):
//   [0,256):     fillscan — per-(batch,sub) scan of partials + LDS-cursor
//                scatter. sub==0 blocks write counts + cursor (starts).
//   [256,4352):  convert X fp32 -> bf16 + int8 (overlaps the fillscan).
//   [4352,4416): convert W fp32 -> bf16.
// ---------------------------------------------------------------------------
__global__ __launch_bounds__(256) void fillconv_kernel(
        const float* __restrict__ X, const float* __restrict__ W,
        const int* __restrict__ E,
        const int* __restrict__ partial,
        int* __restrict__ counts, int* __restrict__ cursor,
        int* __restrict__ srcIdx,
        ushort* __restrict__ Xbf, unsigned char* __restrict__ Xi8,
        ushort* __restrict__ Wbf) {
    int bid = blockIdx.x;
    int t = threadIdx.x;
    if (bid < 256) {
        __shared__ int cur[NNODE];
        __shared__ int tsum[256];
        int b = bid & 15, sub = bid >> 4;
        const int* pb = partial + (size_t)b * SUB * NNODE;

        int tot[8] = {}, pre[8] = {};
        for (int k = 0; k < SUB; ++k) {
            const int4* p = reinterpret_cast<const int4*>(pb + k * NNODE + t * 8);
            int4 a = p[0], c = p[1];
            if (k < sub) {
                pre[0] += a.x; pre[1] += a.y; pre[2] += a.z; pre[3] += a.w;
                pre[4] += c.x; pre[5] += c.y; pre[6] += c.z; pre[7] += c.w;
            }
            tot[0] += a.x; tot[1] += a.y; tot[2] += a.z; tot[3] += a.w;
            tot[4] += c.x; tot[5] += c.y; tot[6] += c.z; tot[7] += c.w;
        }
        int s = 0;
#pragma unroll
        for (int j = 0; j < 8; ++j) s += tot[j];
        tsum[t] = s;
        __syncthreads();
        for (int off = 1; off < 256; off <<= 1) {
            int v = (t >= off) ? tsum[t - off] : 0;
            __syncthreads();
            tsum[t] += v;
            __syncthreads();
        }
        int run = (t == 0) ? 0 : tsum[t - 1];
        bool writer = (sub == 0);
        int base = b * NNODE + t * 8;
#pragma unroll
        for (int j = 0; j < 8; ++j) {
            cur[t * 8 + j] = run + pre[j];
            if (writer) { counts[base + j] = tot[j]; cursor[base + j] = run; }
            run += tot[j];
        }
        __syncthreads();

        const int* eb = E + (size_t)b * 2 * NEDGE;
        const int4* srcs = reinterpret_cast<const int4*>(eb + sub * ESUB);
        const int4* dsts = reinterpret_cast<const int4*>(eb + NEDGE + sub * ESUB);
        int* sb = srcIdx + (size_t)b * NEDGE;
#pragma unroll
        for (int j = 0; j < 4; ++j) {
            int4 sv = srcs[j * 256 + t];
            int4 dv = dsts[j * 256 + t];
            sb[atomicAdd(&cur[dv.x], 1)] = sv.x;
            sb[atomicAdd(&cur[dv.y], 1)] = sv.y;
            sb[atomicAdd(&cur[dv.z], 1)] = sv.z;
            sb[atomicAdd(&cur[dv.w], 1)] = sv.w;
        }
    } else if (bid < 4352) {
        size_t i = (size_t)(bid - 256) * 256 + t;
        const float4* p = reinterpret_cast<const float4*>(X + i * 8);
        float4 u = p[0], v = p[1];
        ushort4 o0 = { f2bf(u.x), f2bf(u.y), f2bf(u.z), f2bf(u.w) };
        ushort4 o1 = { f2bf(v.x), f2bf(v.y), f2bf(v.z), f2bf(v.w) };
        *reinterpret_cast<ushort4*>(Xbf + i * 8)     = o0;
        *reinterpret_cast<ushort4*>(Xbf + i * 8 + 4) = o1;
        unsigned q0 = (q8(u.x) & 255) | ((q8(u.y) & 255) << 8) |
                      ((q8(u.z) & 255) << 16) | ((unsigned)(q8(u.w) & 255) << 24);
        unsigned q1 = (q8(v.x) & 255) | ((q8(v.y) & 255) << 8) |
                      ((q8(v.z) & 255) << 16) | ((unsigned)(q8(v.w) & 255) << 24);
        uint2 q = { q0, q1 };
        *reinterpret_cast<uint2*>(Xi8 + i * 8) = q;
    } else {
        size_t i = (size_t)(bid - 4352) * 256 + t;
        const float4* p = reinterpret_cast<const float4*>(W + i * 8);
        float4 u = p[0], v = p[1];
        ushort4 o0 = { f2bf(u.x), f2bf(u.y), f2bf(u.z), f2bf(u.w) };
        ushort4 o1 = { f2bf(v.x), f2bf(v.y), f2bf(v.z), f2bf(v.w) };
        *reinterpret_cast<ushort4*>(Wbf + i * 8)     = o0;
        *reinterpret_cast<ushort4*>(Wbf + i * 8 + 4) = o1;
    }
}

// ---------------------------------------------------------------------------
// pull-style neighbor mean over int8 features (scale 16), SWAR packed-u16
// integer accumulate (exact), bf16 output. One wave per node; quarter-wave
// per edge; lane owns 16 features (uint4). Tail pads with 0x80808080.
// ---------------------------------------------------------------------------
__global__ __launch_bounds__(256) void aggregate_kernel(
        const unsigned char* __restrict__ Xi8,
        const int* __restrict__ srcIdx,
        const int* __restrict__ cursor,
        const int* __restrict__ counts,
        ushort* __restrict__ Gbf) {
    int bid = blockIdx.x;                     // 8192 blocks
    int blk = (bid & 7) * 1024 + (bid >> 3);  // XCD-contiguous remap (bijective)
    int wave = threadIdx.x >> 6;
    int lane = threadIdx.x & 63;
    int q = lane >> 4;                        // edge slot 0..3
    int l16 = lane & 15;                      // feature group
    int f0 = l16 * 16;                        // 16 bytes (features) per lane
    int node = blk * 4 + wave;                // 0 .. B*N-1
    int b = node >> 11;
    int deg = counts[node];
    int start = cursor[node];
    const unsigned char* xb = Xi8 + (size_t)b * NNODE * DIN;
    const int* sidx = srcIdx + (size_t)b * NEDGE + start;

    unsigned a0 = 0, a1 = 0, a2 = 0, a3 = 0, a4 = 0, a5 = 0, a6 = 0, a7 = 0;
#define M16 0x00FF00FFu
#define ACC16(v) do {                                                         \
        unsigned w0 = (v).x ^ 0x80808080u, w1 = (v).y ^ 0x80808080u;          \
        unsigned w2 = (v).z ^ 0x80808080u, w3 = (v).w ^ 0x80808080u;          \
        a0 += w0 & M16;  a1 += (w0 >> 8) & M16;                               \
        a2 += w1 & M16;  a3 += (w1 >> 8) & M16;                               \
        a4 += w2 & M16;  a5 += (w2 >> 8) & M16;                               \
        a6 += w3 & M16;  a7 += (w3 >> 8) & M16;                               \
    } while (0)

    int i = 0;
    for (; i + 16 <= deg; i += 16) {
        int s0 = sidx[i + q], s1 = sidx[i + 4 + q];
        int s2 = sidx[i + 8 + q], s3 = sidx[i + 12 + q];
        uint4 v0 = *reinterpret_cast<const uint4*>(xb + (size_t)s0 * DIN + f0);
        uint4 v1 = *reinterpret_cast<const uint4*>(xb + (size_t)s1 * DIN + f0);
        uint4 v2 = *reinterpret_cast<const uint4*>(xb + (size_t)s2 * DIN + f0);
        uint4 v3 = *reinterpret_cast<const uint4*>(xb + (size_t)s3 * DIN + f0);
        ACC16(v0); ACC16(v1); ACC16(v2); ACC16(v3);
    }
    for (; i < deg; i += 4) {
        int e = i + q;
        uint4 v = { 0x80808080u, 0x80808080u, 0x80808080u, 0x80808080u };
        if (e < deg) {
            int s0 = sidx[e];
            v = *reinterpret_cast<const uint4*>(xb + (size_t)s0 * DIN + f0);
        }
        ACC16(v);
    }
#undef ACC16
#undef M16
    a0 += (unsigned)__shfl_xor((int)a0, 16, 64); a0 += (unsigned)__shfl_xor((int)a0, 32, 64);
    a1 += (unsigned)__shfl_xor((int)a1, 16, 64); a1 += (unsigned)__shfl_xor((int)a1, 32, 64);
    a2 += (unsigned)__shfl_xor((int)a2, 16, 64); a2 += (unsigned)__shfl_xor((int)a2, 32, 64);
    a3 += (unsigned)__shfl_xor((int)a3, 16, 64); a3 += (unsigned)__shfl_xor((int)a3, 32, 64);
    a4 += (unsigned)__shfl_xor((int)a4, 16, 64); a4 += (unsigned)__shfl_xor((int)a4, 32, 64);
    a5 += (unsigned)__shfl_xor((int)a5, 16, 64); a5 += (unsigned)__shfl_xor((int)a5, 32, 64);
    a6 += (unsigned)__shfl_xor((int)a6, 16, 64); a6 += (unsigned)__shfl_xor((int)a6, 32, 64);
    a7 += (unsigned)__shfl_xor((int)a7, 16, 64); a7 += (unsigned)__shfl_xor((int)a7, 32, 64);

    if (q == 0) {
        float sc = 1.0f / (16.0f * (float)max(deg, 1));   // undo scale-16
        float bias = 128.0f * (float)deg;
        float f[16];
        f[ 0] = ((float)(int)(a0 & 0xFFFFu) - bias) * sc;
        f[ 2] = ((float)(int)(a0 >> 16)     - bias) * sc;
        f[ 1] = ((float)(int)(a1 & 0xFFFFu) - bias) * sc;
        f[ 3] = ((float)(int)(a1 >> 16)     - bias) * sc;
        f[ 4] = ((float)(int)(a2 & 0xFFFFu) - bias) * sc;
        f[ 6] = ((float)(int)(a2 >> 16)     - bias) * sc;
        f[ 5] = ((float)(int)(a3 & 0xFFFFu) - bias) * sc;
        f[ 7] = ((float)(int)(a3 >> 16)     - bias) * sc;
        f[ 8] = ((float)(int)(a4 & 0xFFFFu) - bias) * sc;
        f[10] = ((float)(int)(a4 >> 16)     - bias) * sc;
        f[ 9] = ((float)(int)(a5 & 0xFFFFu) - bias) * sc;
        f[11] = ((float)(int)(a5 >> 16)     - bias) * sc;
        f[12] = ((float)(int)(a6 & 0xFFFFu) - bias) * sc;
        f[14] = ((float)(int)(a6 >> 16)     - bias) * sc;
        f[13] = ((float)(int)(a7 & 0xFFFFu) - bias) * sc;
        f[15] = ((float)(int)(a7 >> 16)     - bias) * sc;
        ushort8 o0, o1;
#pragma unroll
        for (int j = 0; j < 8; ++j) { o0[j] = f2bf(f[j]); o1[j] = f2bf(f[j + 8]); }
        ushort* gp = Gbf + (size_t)node * DIN + f0;
        *reinterpret_cast<ushort8*>(gp)     = o0;
        *reinterpret_cast<ushort8*>(gp + 8) = o1;
    }
}

// ---------------------------------------------------------------------------
// bf16 MFMA GEMM, BK=64: 128x128 tile, 512 blocks (2/CU), 8 K-phases of
// 32 MFMA each (halved barrier count vs BK=32 -> doubled compute:sync).
// LDS: 2 bufs x (16KB A + 16KB B) = 64 KB -> 2 blocks/CU.
// Row = 64 ushorts = 8 chunks of 16B. Swizzle: chunk c_lds holds global
// chunk c ^ ((row>>1)&7) — fragment ds_read_b128 spreads 32 banks at
// 2 lanes/bank (free, m136); staging pre-swizzles the global source and
// keeps LDS dests linear wave-uniform (rule 21).
// ---------------------------------------------------------------------------
__global__ __launch_bounds__(256) void gemm_kernel(
        const ushort* __restrict__ Xbf,
        const ushort* __restrict__ Gbf,
        const ushort* __restrict__ Wbf,
        const float* __restrict__ bias,
        float* __restrict__ out) {
    __shared__ ushort As[2][128 * 64];   // [buf][row*64 + k]
    __shared__ ushort Bs[2][128 * 64];
    const int tid = threadIdx.x;
    const int wid = tid >> 6, lane = tid & 63;

    int orig = blockIdx.x;
    int logical = (orig & 7) * 64 + (orig >> 3);
    int bx = logical >> 1;
    int by = logical & 1;
    const int rowBase = bx * 128;
    const int colBase = by * 128;
    const int wm = wid >> 1, wn = wid & 1;

    f32x4 acc[4][4] = {};

    const ushort* Arow = Xbf + (size_t)rowBase * DIN;
    const ushort* Grow = Gbf + (size_t)rowBase * DIN;
    const ushort* Brow = Wbf + (size_t)colBase * KDIM;

    // staging: call j of wave wid covers rows r = wid*32 + j*8 + (lane>>3),
    // lds chunk = lane&7 (linear); global chunk = (lane&7) ^ ((r>>1)&7).
    const int sr_base = wid * 32 + (lane >> 3);
#define STAGE(k0, buf) do {                                                    \
        const ushort* Ab = ((k0) < DIN) ? (Arow + (k0)) : (Grow + ((k0) - DIN)); \
        const ushort* Bb = Brow + (k0);                                        \
        _Pragma("unroll")                                                      \
        for (int j = 0; j < 4; ++j) {                                          \
            int r = sr_base + j * 8;                                           \
            int cs = ((lane & 7) ^ ((r >> 1) & 7)) * 8;                        \
            ASYNC_COPY16(Ab + (size_t)r * DIN  + cs, &As[buf][(wid * 4 + j) * 512]); \
            ASYNC_COPY16(Bb + (size_t)r * KDIM + cs, &Bs[buf][(wid * 4 + j) * 512]); \
        }                                                                      \
    } while (0)

    // fragment read: row = base + fl, chunk c = (s*4+kq) ^ ((fl>>1)&7)
    const int fl = lane & 15;
    const int kq = lane >> 4;
    const int swz = (fl >> 1) & 7;

    STAGE(0, 0);
    for (int t = 0; t < 8; ++t) {
        const int bt = t & 1;
        if (t < 7) {
            STAGE((t + 1) * 64, bt ^ 1);
            asm volatile("s_waitcnt vmcnt(8)" ::: "memory");   // tile t landed
        } else {
            asm volatile("s_waitcnt vmcnt(0)" ::: "memory");
        }
        __builtin_amdgcn_s_barrier();

#pragma unroll
        for (int s = 0; s < 2; ++s) {
            const int fc = ((s * 4 + kq) ^ swz) * 8;
            short8 a[4], b[4];
#pragma unroll
            for (int m = 0; m < 4; ++m)
                a[m] = *reinterpret_cast<const short8*>(
                    &As[bt][(wm * 64 + m * 16 + fl) * 64 + fc]);
#pragma unroll
            for (int n = 0; n < 4; ++n)
                b[n] = *reinterpret_cast<const short8*>(
                    &Bs[bt][(wn * 64 + n * 16 + fl) * 64 + fc]);
#pragma unroll
            for (int m = 0; m < 4; ++m)
#pragma unroll
                for (int n = 0; n < 4; ++n)
                    acc[m][n] = __builtin_amdgcn_mfma_f32_16x16x32_bf16(
                        a[m], b[n], acc[m][n], 0, 0, 0);
        }
        __builtin_amdgcn_s_barrier();
    }
#undef STAGE

    const int cl = lane & 15, rq = lane >> 4;
#pragma unroll
    for (int n = 0; n < 4; ++n) {
        int col = colBase + wn * 64 + n * 16 + cl;
        float bv = bias[col];
#pragma unroll
        for (int m = 0; m < 4; ++m) {
            int r0o = rowBase + wm * 64 + m * 16 + rq * 4;
#pragma unroll
            for (int j = 0; j < 4; ++j)
                out[(size_t)(r0o + j) * DOUT + col] = acc[m][n][j] + bv;
        }
    }
}

// ---------------------------------------------------------------------------
extern "C" void kernel_launch(void* const* d_in, const int* in_sizes, int n_in,
                              void* d_out, int out_size, void* d_ws, size_t ws_size,
                              hipStream_t stream) {
    const float* X    = (const float*)d_in[0];   // (B, N, DIN)
    const int*   E    = (const int*)d_in[1];     // (B, 2, NEDGE) int32
    const float* W    = (const float*)d_in[2];   // (DOUT, KDIM)
    const float* bias = (const float*)d_in[3];   // (DOUT,)
    float* out = (float*)d_out;                  // (B, N, DOUT)

    char* ws = (char*)d_ws;
    ushort* Xbf  = (ushort*)ws;                                 // 16.78 MB
    ushort* Gbf  = Xbf + (size_t)BATCH * NNODE * DIN;           // 16.78 MB
    ushort* Wbf  = Gbf + (size_t)BATCH * NNODE * DIN;           // 256 KB
    int* counts  = (int*)(Wbf + (size_t)DOUT * KDIM);           // 128 KB
    int* cursor  = counts + BATCH * NNODE;                      // 128 KB
    int* srcIdx  = cursor + BATCH * NNODE;                      // 4 MB
    unsigned char* Xi8 = (unsigned char*)(srcIdx + (size_t)BATCH * NEDGE); // 8.39 MB
    // partial overlays into Gbf (dead until aggregate writes it)
    int* partial = (int*)Gbf;                                   // 2 MB

    // 1: partial histograms only (short)
    hist_kernel<<<256, 256, 0, stream>>>(E, partial);

    // 2: fillscan (256 blocks) overlapped with X/W converts (4160 blocks)
    fillconv_kernel<<<4416, 256, 0, stream>>>(
        X, W, E, partial, counts, cursor, srcIdx, Xbf, Xi8, Wbf);

    // 3: int8 SWAR gather-mean -> bf16 G
    aggregate_kernel<<<(BATCH * NNODE) / 4, 256, 0, stream>>>(
        Xi8, srcIdx, cursor, counts, Gbf);

    // 4: bf16 MFMA GEMM, BK=64
    dim3 ggrid(512);
    gemm_kernel<<<ggrid, 256, 0, stream>>>(Xbf, Gbf, Wbf, bias, out);
}